// Round 4
// baseline (180.380 us; speedup 1.0000x reference)
//
#include <hip/hip_runtime.h>

#define LEAKY(t) ((t) > 0.0f ? (t) : 0.01f*(t))

typedef __attribute__((ext_vector_type(8))) short short8;
typedef __attribute__((ext_vector_type(4))) float floatx4;

// fp32 -> bf16 (round to nearest even), bits in a short
static __device__ __forceinline__ short f2bf(float f) {
  unsigned u = __float_as_uint(f);
  u += 0x7FFFu + ((u >> 16) & 1u);
  return (short)(u >> 16);
}

// ---------------------------------------------------------------------------
// Workspace (float index):
//   d    @ 0      64*384 = 24576   descriptor (zeroed by prep, atomicAdd by embed)
//   h1f  @ 24576  64*256
//   h2f  @ 40960  64*256
//   h3f  @ 57344  64*128
//   cnt  @ 65536  1 uint           arrival counter for fit3 finalize
//   g_WT @ 65540  33792 shorts     B-fragment tables (lane-indexed):
//     W1B [p][ot(2)][lane]  item = p*128 + ot*64 + lane          (384 items)
//     W2B [p][ot(4)][lane]  item = 384 + p*256 + ot*64 + lane    (768 items)
//     W3B [p][ot(8)][ks(2)][lane] = 1152 + p*1024+ot*128+ks*64+l (3072 items)
//   (one item = short8 = 16 B)
// ---------------------------------------------------------------------------

// ---------------------------------------------------------------------------
// Prep: build MFMA B-fragment tables, zero d and cnt.
// B-frag layout for 16x16x32: lane=(col=o_local, quad), element j -> k=quad*8+j.
// Layer-1 trick: k<3 -> We1[k][o], k==3 -> be1[o] (A supplies 1.0 at k=3).
// ---------------------------------------------------------------------------
__global__ __launch_bounds__(256) void prep_kernel(
    const float* __restrict__ We1, const float* __restrict__ be1,
    const float* __restrict__ We2, const float* __restrict__ We3,
    short* __restrict__ g_WT, float* __restrict__ d,
    unsigned int* __restrict__ cnt)
{
  const int gt = blockIdx.x * 256 + threadIdx.x;
  const int GS = gridDim.x * 256;
  if (gt == 0) *cnt = 0;
  for (int i = gt; i < 6144; i += GS) {
    const float4 z = {0.f, 0.f, 0.f, 0.f};
    ((float4*)d)[i] = z;
  }
  for (int it = gt; it < 4224; it += GS) {
    short8 v;
    if (it < 384) {
      const int p = it >> 7, r = it & 127, ot = (r >> 6) & 1, ln = r & 63;
      const int col = ln & 15, quad = ln >> 4, o = ot * 16 + col;
      #pragma unroll
      for (int j = 0; j < 8; ++j) {
        const int k = quad * 8 + j;
        float f = 0.0f;
        if (k < 3) f = We1[p * 96 + k * 32 + o];
        else if (k == 3) f = be1[p * 32 + o];
        v[j] = f2bf(f);
      }
    } else if (it < 1152) {
      const int t = it - 384;
      const int p = t >> 8, r = t & 255, ot = r >> 6, ln = r & 63;
      const int col = ln & 15, quad = ln >> 4, o = ot * 16 + col;
      #pragma unroll
      for (int j = 0; j < 8; ++j) {
        const int k = quad * 8 + j;
        v[j] = f2bf(We2[p * 2048 + k * 64 + o]);
      }
    } else {
      const int t = it - 1152;
      const int p = t >> 10, r = t & 1023, ot = r >> 7, rr = r & 127;
      const int ks = rr >> 6, ln = rr & 63;
      const int col = ln & 15, quad = ln >> 4, o = ot * 16 + col;
      #pragma unroll
      for (int j = 0; j < 8; ++j) {
        const int k = ks * 32 + quad * 8 + j;
        v[j] = f2bf(We3[p * 8192 + k * 128 + o]);
      }
    }
    *(short8*)(g_WT + it * 8) = v;
  }
}

// ---------------------------------------------------------------------------
// Embedding + descriptor, all-MFMA, weights in registers (no LDS staging).
// grid (64 n, 2 par, 6 chunk), 256 thr; chunk = 144 pairs = 9 m-tiles.
// LDS only holds activations: 36.9 KB -> 4 blocks/CU.
// keep = (dist<=25) && (m!=n); pair-type p depends only on (n%2, j%2).
// Descriptor atomicAdd'ed into global d[n][o*3+c] (zeroed by prep).
// ---------------------------------------------------------------------------
__global__ __launch_bounds__(256, 4) void embed_kernel(
    const float* __restrict__ x, const float* __restrict__ lattice,
    const short* __restrict__ g_WT,
    const float* __restrict__ be2, const float* __restrict__ be3,
    const int* __restrict__ types, float* __restrict__ d)
{
  __shared__ __align__(16) float rel4[144 * 4];   // {rel0,rel1,rel2,1.0}
  __shared__ __align__(16) float rk4[144 * 4];    // rel*keep
  __shared__ __align__(16) short h1s[144 * 40];   // bf16, stride 40
  __shared__ __align__(16) short h2s[144 * 72];   // bf16, stride 72

  const int n = blockIdx.x, par = blockIdx.y, chunk = blockIdx.z;
  const int tid = threadIdx.x;
  const int lane = tid & 63, w = tid >> 6;
  const int col = lane & 15, quad = lane >> 4;

  const int tn = types[n];
  const int tj = types[par];
  const int lo = tn < tj ? tn : tj;
  const int hi = tn < tj ? tj : tn;
  const int p  = lo * 2 - (lo * (lo - 1)) / 2 + (hi - lo);

  // ---- B-fragments straight from global into registers (L2-hot) ----
  const short8* WT8 = (const short8*)g_WT;
  const short8 w1b0 = WT8[(p * 2 + 0) * 64 + lane];
  const short8 w1b1 = WT8[(p * 2 + 1) * 64 + lane];
  short8 w2b[4];
  #pragma unroll
  for (int ot = 0; ot < 4; ++ot) w2b[ot] = WT8[384 + (p * 4 + ot) * 64 + lane];
  short8 w3b[2][2];
  #pragma unroll
  for (int nt = 0; nt < 2; ++nt)
    #pragma unroll
    for (int ks = 0; ks < 2; ++ks)
      w3b[nt][ks] = WT8[1152 + ((p * 8 + 2 * w + nt) * 2 + ks) * 64 + lane];
  float bias2[4];
  #pragma unroll
  for (int ot = 0; ot < 4; ++ot) bias2[ot] = be2[p * 64 + ot * 16 + col];
  float bias3[2];
  #pragma unroll
  for (int nt = 0; nt < 2; ++nt) bias3[nt] = be3[p * 128 + w * 32 + nt * 16 + col];

  // ---- rel / keep, one thread per pair ----
  if (tid < 144) {
    const int q  = chunk * 144 + tid;
    const int c  = q >> 5;
    const int jj = q & 31;
    const int j  = 2 * jj + par;
    const float f0 = (float)(c / 9);
    const float f1 = (float)((c / 3) % 3);
    const float f2c = (float)(c % 3);
    const float rel0 = x[j*3+0] - x[n*3+0] + f0*lattice[0] + f1*lattice[3] + f2c*lattice[6];
    const float rel1 = x[j*3+1] - x[n*3+1] + f0*lattice[1] + f1*lattice[4] + f2c*lattice[7];
    const float rel2 = x[j*3+2] - x[n*3+2] + f0*lattice[2] + f1*lattice[5] + f2c*lattice[8];
    const float dist2 = rel0*rel0 + rel1*rel1 + rel2*rel2;
    const int m = c * 64 + j;
    const bool keep = (dist2 <= 625.0f) && (m != n);
    const float kf = keep ? 1.0f : 0.0f;
    rel4[tid*4+0] = rel0; rel4[tid*4+1] = rel1;
    rel4[tid*4+2] = rel2; rel4[tid*4+3] = 1.0f;
    rk4[tid*4+0] = rel0*kf; rk4[tid*4+1] = rel1*kf;
    rk4[tid*4+2] = rel2*kf; rk4[tid*4+3] = 0.0f;
  }
  __syncthreads();

  // ---- layer 1 (3->32) via MFMA, m-tiles split across waves ----
  for (int mt = w; mt < 9; mt += 4) {
    const float4 r4 = *(const float4*)&rel4[(mt*16 + col) * 4];
    short8 a = {0, 0, 0, 0, 0, 0, 0, 0};
    if (quad == 0) {
      a[0] = f2bf(r4.x); a[1] = f2bf(r4.y); a[2] = f2bf(r4.z);
      a[3] = (short)0x3F80;   // 1.0 -> picks up bias row k=3
    }
    const floatx4 z = {0.f, 0.f, 0.f, 0.f};
    const floatx4 c0 = __builtin_amdgcn_mfma_f32_16x16x32_bf16(a, w1b0, z, 0, 0, 0);
    const floatx4 c1 = __builtin_amdgcn_mfma_f32_16x16x32_bf16(a, w1b1, z, 0, 0, 0);
    #pragma unroll
    for (int r = 0; r < 4; ++r) {
      const int pair = mt*16 + quad*4 + r;
      h1s[pair*40 +      col] = f2bf(LEAKY(c0[r]));
      h1s[pair*40 + 16 + col] = f2bf(LEAKY(c1[r]));
    }
  }
  __syncthreads();

  // ---- layer 2 (32->64) via MFMA, m-tiles split across waves ----
  for (int mt = w; mt < 9; mt += 4) {
    const short8 a = *(const short8*)&h1s[(mt*16 + col) * 40 + quad*8];
    #pragma unroll
    for (int ot = 0; ot < 4; ++ot) {
      floatx4 acc = {bias2[ot], bias2[ot], bias2[ot], bias2[ot]};
      acc = __builtin_amdgcn_mfma_f32_16x16x32_bf16(a, w2b[ot], acc, 0, 0, 0);
      #pragma unroll
      for (int r = 0; r < 4; ++r) {
        const int pair = mt*16 + quad*4 + r;
        h2s[pair*72 + ot*16 + col] = f2bf(LEAKY(acc[r]));
      }
    }
  }
  __syncthreads();

  // ---- layer 3 (64->128) MFMA, wave w owns o-tiles {2w,2w+1}; fused desc ----
  float vacc[2][3] = {{0,0,0},{0,0,0}};
  for (int mt = 0; mt < 9; ++mt) {
    const short8 a0 = *(const short8*)&h2s[(mt*16 + col) * 72 +      quad*8];
    const short8 a1 = *(const short8*)&h2s[(mt*16 + col) * 72 + 32 + quad*8];
    float4 rks[4];
    #pragma unroll
    for (int r = 0; r < 4; ++r)
      rks[r] = *(const float4*)&rk4[(mt*16 + quad*4 + r) * 4];
    #pragma unroll
    for (int nt = 0; nt < 2; ++nt) {
      floatx4 acc = {bias3[nt], bias3[nt], bias3[nt], bias3[nt]};
      acc = __builtin_amdgcn_mfma_f32_16x16x32_bf16(a0, w3b[nt][0], acc, 0, 0, 0);
      acc = __builtin_amdgcn_mfma_f32_16x16x32_bf16(a1, w3b[nt][1], acc, 0, 0, 0);
      #pragma unroll
      for (int r = 0; r < 4; ++r) {
        const float h3 = LEAKY(acc[r]);
        vacc[nt][0] += h3 * rks[r].x;
        vacc[nt][1] += h3 * rks[r].y;
        vacc[nt][2] += h3 * rks[r].z;
      }
    }
  }
  #pragma unroll
  for (int nt = 0; nt < 2; ++nt)
    #pragma unroll
    for (int c = 0; c < 3; ++c) {
      float v = vacc[nt][c];
      v += __shfl_xor(v, 16, 64);
      v += __shfl_xor(v, 32, 64);
      vacc[nt][c] = v;
    }
  if (lane < 32) {
    const int nts = lane >> 4, colw = lane & 15;
    const int o = w*32 + nts*16 + colw;
    #pragma unroll
    for (int c = 0; c < 3; ++c)
      atomicAdd(&d[n*384 + o*3 + c], nts ? vacc[1][c] : vacc[0][c]);
  }
}

// ---------------------------------------------------------------------------
// Fit layer 1: d(384) -> 256. grid (64, 8 slices of 32 o), 256 thr.
// ---------------------------------------------------------------------------
__global__ __launch_bounds__(256) void fit1_kernel(
    const float* __restrict__ d, const float* __restrict__ W,
    const float* __restrict__ b, float* __restrict__ out)
{
  __shared__ float din[384];
  __shared__ floatx4 red[256];
  const int n = blockIdx.x, os = blockIdx.y * 32, tid = threadIdx.x;
  for (int i = tid; i < 384; i += 256) din[i] = d[n*384 + i];
  __syncthreads();
  const int g = tid & 7, s = tid >> 3;          // 8 o4-groups x 32 i-slices(12)
  const float* Wp = W + (size_t)n * 98304 + os + 4 * g;
  floatx4 acc = {0, 0, 0, 0};
  #pragma unroll
  for (int k = 0; k < 12; ++k) {
    const int i = s * 12 + k;
    acc += din[i] * *(const floatx4*)(Wp + (size_t)i * 256);
  }
  red[tid] = acc;
  __syncthreads();
  #pragma unroll
  for (int off = 128; off >= 8; off >>= 1) {
    if (tid < off) red[tid] += red[tid + off];
    __syncthreads();
  }
  if (tid < 8) {
    const floatx4 v = red[tid];
    const int o = os + 4 * tid;
    const float4 bb = *(const float4*)&b[n*256 + o];
    float4 r;
    r.x = LEAKY(v[0] + bb.x); r.y = LEAKY(v[1] + bb.y);
    r.z = LEAKY(v[2] + bb.z); r.w = LEAKY(v[3] + bb.w);
    *(float4*)&out[n*256 + o] = r;
  }
}

// ---------------------------------------------------------------------------
// Fit layer 2: 256 -> 256. grid (64, 8 slices of 32 o), 256 thr.
// ---------------------------------------------------------------------------
__global__ __launch_bounds__(256) void fit2_kernel(
    const float* __restrict__ in, const float* __restrict__ W,
    const float* __restrict__ b, float* __restrict__ out)
{
  __shared__ float din[256];
  __shared__ floatx4 red[256];
  const int n = blockIdx.x, os = blockIdx.y * 32, tid = threadIdx.x;
  din[tid] = in[n*256 + tid];
  __syncthreads();
  const int g = tid & 7, s = tid >> 3;          // 8 o4-groups x 32 i-slices(8)
  const float* Wp = W + (size_t)n * 65536 + os + 4 * g;
  floatx4 acc = {0, 0, 0, 0};
  #pragma unroll
  for (int k = 0; k < 8; ++k) {
    const int i = s * 8 + k;
    acc += din[i] * *(const floatx4*)(Wp + (size_t)i * 256);
  }
  red[tid] = acc;
  __syncthreads();
  #pragma unroll
  for (int off = 128; off >= 8; off >>= 1) {
    if (tid < off) red[tid] += red[tid + off];
    __syncthreads();
  }
  if (tid < 8) {
    const floatx4 v = red[tid];
    const int o = os + 4 * tid;
    const float4 bb = *(const float4*)&b[n*256 + o];
    float4 r;
    r.x = LEAKY(v[0] + bb.x); r.y = LEAKY(v[1] + bb.y);
    r.z = LEAKY(v[2] + bb.z); r.w = LEAKY(v[3] + bb.w);
    *(float4*)&out[n*256 + o] = r;
  }
}

// ---------------------------------------------------------------------------
// Fit layer 3 (256->128) + last-block fit4 (128->3) + mean-subtract.
// grid (64, 8 slices of 16 o), 256 thr. h3 slices published with agent-scope
// atomics; last-arriving block finalizes (R3-proven pattern).
// ---------------------------------------------------------------------------
__global__ __launch_bounds__(256) void fit34_kernel(
    const float* __restrict__ in, const float* __restrict__ W,
    const float* __restrict__ b,
    const float* __restrict__ Wl4, const float* __restrict__ bl4,
    float* __restrict__ h3f, unsigned int* __restrict__ cnt,
    float* __restrict__ out)
{
  __shared__ float din[256];
  __shared__ floatx4 red[256];
  __shared__ float fin[256];
  __shared__ int amlast;
  const int n = blockIdx.x, os = blockIdx.y * 16, tid = threadIdx.x;
  din[tid] = in[n*256 + tid];
  __syncthreads();
  const int g = tid & 3, s = tid >> 2;          // 4 o4-groups x 64 i-slices(4)
  const float* Wp = W + (size_t)n * 32768 + os + 4 * g;
  floatx4 acc = {0, 0, 0, 0};
  #pragma unroll
  for (int k = 0; k < 4; ++k) {
    const int i = s * 4 + k;
    acc += din[i] * *(const floatx4*)(Wp + (size_t)i * 128);
  }
  red[tid] = acc;
  __syncthreads();
  #pragma unroll
  for (int off = 128; off >= 4; off >>= 1) {
    if (tid < off) red[tid] += red[tid + off];
    __syncthreads();
  }
  if (tid < 4) {
    const floatx4 v = red[tid];
    const int o = os + 4 * tid;
    const float4 bb = *(const float4*)&b[n*128 + o];
    #pragma unroll
    for (int u = 0; u < 4; ++u)
      __hip_atomic_store(&h3f[n*128 + o + u],
                         LEAKY(v[u] + ((const float*)&bb)[u]),
                         __ATOMIC_RELAXED, __HIP_MEMORY_SCOPE_AGENT);
  }
  __threadfence();
  if (tid == 0) {
    const unsigned old = __hip_atomic_fetch_add(cnt, 1u, __ATOMIC_ACQ_REL,
                                                __HIP_MEMORY_SCOPE_AGENT);
    amlast = (old == 511u);
  }
  __syncthreads();
  if (amlast) {
    // ---- fit layer 4: 128 -> 3 per atom, then mean-subtract ----
    float* part = (float*)red;            // reuse (4 KB >= 768 floats)
    const int nn = tid >> 2, q = tid & 3;
    const float* Wn = Wl4 + (size_t)nn * 384;
    float a0 = 0.f, a1 = 0.f, a2 = 0.f;
    for (int k = 0; k < 32; ++k) {
      const int i = q * 32 + k;
      const float hv = __hip_atomic_load(&h3f[nn*128 + i], __ATOMIC_RELAXED,
                                         __HIP_MEMORY_SCOPE_AGENT);
      a0 += hv * Wn[i*3 + 0];
      a1 += hv * Wn[i*3 + 1];
      a2 += hv * Wn[i*3 + 2];
    }
    part[tid*3+0] = a0; part[tid*3+1] = a1; part[tid*3+2] = a2;
    __syncthreads();
    if (tid < 192) {
      const int a = tid / 3, o = tid % 3;
      fin[tid] = part[(a*4+0)*3+o] + part[(a*4+1)*3+o]
               + part[(a*4+2)*3+o] + part[(a*4+3)*3+o] + bl4[tid];
    }
    __syncthreads();
    if (tid < 3) {
      float sm = 0.f;
      for (int a = 0; a < 64; ++a) sm += fin[a*3 + tid];
      fin[200 + tid] = sm * (1.0f / 64.0f);
    }
    __syncthreads();
    if (tid < 192) out[tid] = fin[tid] - fin[200 + (tid % 3)];
  }
}

// ---------------------------------------------------------------------------
extern "C" void kernel_launch(void* const* d_in, const int* in_sizes, int n_in,
                              void* d_out, int out_size, void* d_ws, size_t ws_size,
                              hipStream_t stream) {
  const float* x       = (const float*)d_in[0];
  const float* lattice = (const float*)d_in[1];
  const float* We1 = (const float*)d_in[2];
  const float* be1 = (const float*)d_in[3];
  const float* We2 = (const float*)d_in[4];
  const float* be2 = (const float*)d_in[5];
  const float* We3 = (const float*)d_in[6];
  const float* be3 = (const float*)d_in[7];
  const float* Wl1 = (const float*)d_in[8];
  const float* bl1 = (const float*)d_in[9];
  const float* Wl2 = (const float*)d_in[10];
  const float* bl2 = (const float*)d_in[11];
  const float* Wl3 = (const float*)d_in[12];
  const float* bl3 = (const float*)d_in[13];
  const float* Wl4 = (const float*)d_in[14];
  const float* bl4 = (const float*)d_in[15];
  const int*   types = (const int*)d_in[16];

  float* wsf = (float*)d_ws;
  float*        d    = wsf;                       // 24576
  float*        h1f  = wsf + 24576;               // 16384
  float*        h2f  = wsf + 40960;               // 16384
  float*        h3f  = wsf + 57344;               // 8192
  unsigned int* cnt  = (unsigned int*)(wsf + 65536);
  short*        g_WT = (short*)(wsf + 65540);     // 33792 shorts

  prep_kernel<<<32, 256, 0, stream>>>(We1, be1, We2, We3, g_WT, d, cnt);
  embed_kernel<<<dim3(64, 2, 6), 256, 0, stream>>>(
      x, lattice, g_WT, be2, be3, types, d);
  fit1_kernel<<<dim3(64, 8), 256, 0, stream>>>(d, Wl1, bl1, h1f);
  fit2_kernel<<<dim3(64, 8), 256, 0, stream>>>(h1f, Wl2, bl2, h2f);
  fit34_kernel<<<dim3(64, 8), 256, 0, stream>>>(h2f, Wl3, bl3, Wl4, bl4,
                                                h3f, cnt, (float*)d_out);
}

// Round 5
// 143.295 us; speedup vs baseline: 1.2588x; 1.2588x over previous
//
#include <hip/hip_runtime.h>

#define LEAKY(t) ((t) > 0.0f ? (t) : 0.01f*(t))

typedef __attribute__((ext_vector_type(8))) short short8;
typedef __attribute__((ext_vector_type(4))) float floatx4;

// fp32 -> bf16 (round to nearest even), bits in a short
static __device__ __forceinline__ short f2bf(float f) {
  unsigned u = __float_as_uint(f);
  u += 0x7FFFu + ((u >> 16) & 1u);
  return (short)(u >> 16);
}

// ---------------------------------------------------------------------------
// Workspace (float index):
//   d     @ 0      64*384 = 24576  descriptor (zeroed by prep, atomicAdd)
//   h1f   @ 24576  64*256
//   pre_g @ 40960  192             per-atom raw outputs (fit234 finalize)
//   cnt   @ 41152  1 uint          arrival counter (zeroed by prep)
//   g_WT  @ 41156  33792 shorts    MFMA B-fragment tables (lane-indexed)
// ---------------------------------------------------------------------------

// ---------------------------------------------------------------------------
// Prep: build MFMA B-fragment tables, zero d and cnt.
// B-frag layout for 16x16x32: lane=(col=o_local, quad), element j -> k=quad*8+j.
// Layer-1 trick: k<3 -> We1[k][o], k==3 -> be1[o] (A supplies 1.0 at k=3).
// ---------------------------------------------------------------------------
__global__ __launch_bounds__(256) void prep_kernel(
    const float* __restrict__ We1, const float* __restrict__ be1,
    const float* __restrict__ We2, const float* __restrict__ We3,
    short* __restrict__ g_WT, float* __restrict__ d,
    unsigned int* __restrict__ cnt)
{
  const int gt = blockIdx.x * 256 + threadIdx.x;
  const int GS = gridDim.x * 256;
  if (gt == 0) *cnt = 0;
  for (int i = gt; i < 6144; i += GS) {
    const float4 z = {0.f, 0.f, 0.f, 0.f};
    ((float4*)d)[i] = z;
  }
  for (int it = gt; it < 4224; it += GS) {
    short8 v;
    if (it < 384) {
      const int p = it >> 7, r = it & 127, ot = (r >> 6) & 1, ln = r & 63;
      const int col = ln & 15, quad = ln >> 4, o = ot * 16 + col;
      #pragma unroll
      for (int j = 0; j < 8; ++j) {
        const int k = quad * 8 + j;
        float f = 0.0f;
        if (k < 3) f = We1[p * 96 + k * 32 + o];
        else if (k == 3) f = be1[p * 32 + o];
        v[j] = f2bf(f);
      }
    } else if (it < 1152) {
      const int t = it - 384;
      const int p = t >> 8, r = t & 255, ot = r >> 6, ln = r & 63;
      const int col = ln & 15, quad = ln >> 4, o = ot * 16 + col;
      #pragma unroll
      for (int j = 0; j < 8; ++j) {
        const int k = quad * 8 + j;
        v[j] = f2bf(We2[p * 2048 + k * 64 + o]);
      }
    } else {
      const int t = it - 1152;
      const int p = t >> 10, r = t & 1023, ot = r >> 7, rr = r & 127;
      const int ks = rr >> 6, ln = rr & 63;
      const int col = ln & 15, quad = ln >> 4, o = ot * 16 + col;
      #pragma unroll
      for (int j = 0; j < 8; ++j) {
        const int k = ks * 32 + quad * 8 + j;
        v[j] = f2bf(We3[p * 8192 + k * 128 + o]);
      }
    }
    *(short8*)(g_WT + it * 8) = v;
  }
}

// ---------------------------------------------------------------------------
// Embedding + descriptor, all-MFMA, weights in registers (no LDS staging).
// grid (64 n, 2 par, 6 chunk), 256 thr; chunk = 144 pairs = 9 m-tiles.
// LDS only holds activations: 36.9 KB -> 4 blocks/CU.
// keep = (dist<=25) && (m!=n); pair-type p depends only on (n%2, j%2).
// Descriptor atomicAdd'ed into global d[n][o*3+c] (zeroed by prep).
// ---------------------------------------------------------------------------
__global__ __launch_bounds__(256, 4) void embed_kernel(
    const float* __restrict__ x, const float* __restrict__ lattice,
    const short* __restrict__ g_WT,
    const float* __restrict__ be2, const float* __restrict__ be3,
    const int* __restrict__ types, float* __restrict__ d)
{
  __shared__ __align__(16) float rel4[144 * 4];   // {rel0,rel1,rel2,1.0}
  __shared__ __align__(16) float rk4[144 * 4];    // rel*keep
  __shared__ __align__(16) short h1s[144 * 40];   // bf16, stride 40
  __shared__ __align__(16) short h2s[144 * 72];   // bf16, stride 72

  const int n = blockIdx.x, par = blockIdx.y, chunk = blockIdx.z;
  const int tid = threadIdx.x;
  const int lane = tid & 63, w = tid >> 6;
  const int col = lane & 15, quad = lane >> 4;

  const int tn = types[n];
  const int tj = types[par];
  const int lo = tn < tj ? tn : tj;
  const int hi = tn < tj ? tj : tn;
  const int p  = lo * 2 - (lo * (lo - 1)) / 2 + (hi - lo);

  // ---- B-fragments straight from global into registers (L2-hot) ----
  const short8* WT8 = (const short8*)g_WT;
  const short8 w1b0 = WT8[(p * 2 + 0) * 64 + lane];
  const short8 w1b1 = WT8[(p * 2 + 1) * 64 + lane];
  short8 w2b[4];
  #pragma unroll
  for (int ot = 0; ot < 4; ++ot) w2b[ot] = WT8[384 + (p * 4 + ot) * 64 + lane];
  short8 w3b[2][2];
  #pragma unroll
  for (int nt = 0; nt < 2; ++nt)
    #pragma unroll
    for (int ks = 0; ks < 2; ++ks)
      w3b[nt][ks] = WT8[1152 + ((p * 8 + 2 * w + nt) * 2 + ks) * 64 + lane];
  float bias2[4];
  #pragma unroll
  for (int ot = 0; ot < 4; ++ot) bias2[ot] = be2[p * 64 + ot * 16 + col];
  float bias3[2];
  #pragma unroll
  for (int nt = 0; nt < 2; ++nt) bias3[nt] = be3[p * 128 + w * 32 + nt * 16 + col];

  // ---- rel / keep, one thread per pair ----
  if (tid < 144) {
    const int q  = chunk * 144 + tid;
    const int c  = q >> 5;
    const int jj = q & 31;
    const int j  = 2 * jj + par;
    const float f0 = (float)(c / 9);
    const float f1 = (float)((c / 3) % 3);
    const float f2c = (float)(c % 3);
    const float rel0 = x[j*3+0] - x[n*3+0] + f0*lattice[0] + f1*lattice[3] + f2c*lattice[6];
    const float rel1 = x[j*3+1] - x[n*3+1] + f0*lattice[1] + f1*lattice[4] + f2c*lattice[7];
    const float rel2 = x[j*3+2] - x[n*3+2] + f0*lattice[2] + f1*lattice[5] + f2c*lattice[8];
    const float dist2 = rel0*rel0 + rel1*rel1 + rel2*rel2;
    const int m = c * 64 + j;
    const bool keep = (dist2 <= 625.0f) && (m != n);
    const float kf = keep ? 1.0f : 0.0f;
    rel4[tid*4+0] = rel0; rel4[tid*4+1] = rel1;
    rel4[tid*4+2] = rel2; rel4[tid*4+3] = 1.0f;
    rk4[tid*4+0] = rel0*kf; rk4[tid*4+1] = rel1*kf;
    rk4[tid*4+2] = rel2*kf; rk4[tid*4+3] = 0.0f;
  }
  __syncthreads();

  // ---- layer 1 (3->32) via MFMA, m-tiles split across waves ----
  for (int mt = w; mt < 9; mt += 4) {
    const float4 r4 = *(const float4*)&rel4[(mt*16 + col) * 4];
    short8 a = {0, 0, 0, 0, 0, 0, 0, 0};
    if (quad == 0) {
      a[0] = f2bf(r4.x); a[1] = f2bf(r4.y); a[2] = f2bf(r4.z);
      a[3] = (short)0x3F80;   // 1.0 -> picks up bias row k=3
    }
    const floatx4 z = {0.f, 0.f, 0.f, 0.f};
    const floatx4 c0 = __builtin_amdgcn_mfma_f32_16x16x32_bf16(a, w1b0, z, 0, 0, 0);
    const floatx4 c1 = __builtin_amdgcn_mfma_f32_16x16x32_bf16(a, w1b1, z, 0, 0, 0);
    #pragma unroll
    for (int r = 0; r < 4; ++r) {
      const int pair = mt*16 + quad*4 + r;
      h1s[pair*40 +      col] = f2bf(LEAKY(c0[r]));
      h1s[pair*40 + 16 + col] = f2bf(LEAKY(c1[r]));
    }
  }
  __syncthreads();

  // ---- layer 2 (32->64) via MFMA, m-tiles split across waves ----
  for (int mt = w; mt < 9; mt += 4) {
    const short8 a = *(const short8*)&h1s[(mt*16 + col) * 40 + quad*8];
    #pragma unroll
    for (int ot = 0; ot < 4; ++ot) {
      floatx4 acc = {bias2[ot], bias2[ot], bias2[ot], bias2[ot]};
      acc = __builtin_amdgcn_mfma_f32_16x16x32_bf16(a, w2b[ot], acc, 0, 0, 0);
      #pragma unroll
      for (int r = 0; r < 4; ++r) {
        const int pair = mt*16 + quad*4 + r;
        h2s[pair*72 + ot*16 + col] = f2bf(LEAKY(acc[r]));
      }
    }
  }
  __syncthreads();

  // ---- layer 3 (64->128) MFMA, wave w owns o-tiles {2w,2w+1}; fused desc ----
  float vacc[2][3] = {{0,0,0},{0,0,0}};
  for (int mt = 0; mt < 9; ++mt) {
    const short8 a0 = *(const short8*)&h2s[(mt*16 + col) * 72 +      quad*8];
    const short8 a1 = *(const short8*)&h2s[(mt*16 + col) * 72 + 32 + quad*8];
    float4 rks[4];
    #pragma unroll
    for (int r = 0; r < 4; ++r)
      rks[r] = *(const float4*)&rk4[(mt*16 + quad*4 + r) * 4];
    #pragma unroll
    for (int nt = 0; nt < 2; ++nt) {
      floatx4 acc = {bias3[nt], bias3[nt], bias3[nt], bias3[nt]};
      acc = __builtin_amdgcn_mfma_f32_16x16x32_bf16(a0, w3b[nt][0], acc, 0, 0, 0);
      acc = __builtin_amdgcn_mfma_f32_16x16x32_bf16(a1, w3b[nt][1], acc, 0, 0, 0);
      #pragma unroll
      for (int r = 0; r < 4; ++r) {
        const float h3 = LEAKY(acc[r]);
        vacc[nt][0] += h3 * rks[r].x;
        vacc[nt][1] += h3 * rks[r].y;
        vacc[nt][2] += h3 * rks[r].z;
      }
    }
  }
  #pragma unroll
  for (int nt = 0; nt < 2; ++nt)
    #pragma unroll
    for (int c = 0; c < 3; ++c) {
      float v = vacc[nt][c];
      v += __shfl_xor(v, 16, 64);
      v += __shfl_xor(v, 32, 64);
      vacc[nt][c] = v;
    }
  if (lane < 32) {
    const int nts = lane >> 4, colw = lane & 15;
    const int o = w*32 + nts*16 + colw;
    #pragma unroll
    for (int c = 0; c < 3; ++c)
      atomicAdd(&d[n*384 + o*3 + c], nts ? vacc[1][c] : vacc[0][c]);
  }
}

// ---------------------------------------------------------------------------
// Fit layer 1: d(384) -> 256. grid (64, 8 slices of 32 o), 256 thr. No fences.
// ---------------------------------------------------------------------------
__global__ __launch_bounds__(256) void fit1_kernel(
    const float* __restrict__ d, const float* __restrict__ W,
    const float* __restrict__ b, float* __restrict__ out)
{
  __shared__ float din[384];
  __shared__ floatx4 red[256];
  const int n = blockIdx.x, os = blockIdx.y * 32, tid = threadIdx.x;
  for (int i = tid; i < 384; i += 256) din[i] = d[n*384 + i];
  __syncthreads();
  const int g = tid & 7, s = tid >> 3;          // 8 o4-groups x 32 i-slices(12)
  const float* Wp = W + (size_t)n * 98304 + os + 4 * g;
  floatx4 acc = {0, 0, 0, 0};
  #pragma unroll
  for (int k = 0; k < 12; ++k) {
    const int i = s * 12 + k;
    acc += din[i] * *(const floatx4*)(Wp + (size_t)i * 256);
  }
  red[tid] = acc;
  __syncthreads();
  #pragma unroll
  for (int off = 128; off >= 8; off >>= 1) {
    if (tid < off) red[tid] += red[tid + off];
    __syncthreads();
  }
  if (tid < 8) {
    const floatx4 v = red[tid];
    const int o = os + 4 * tid;
    const float4 bb = *(const float4*)&b[n*256 + o];
    float4 r;
    r.x = LEAKY(v[0] + bb.x); r.y = LEAKY(v[1] + bb.y);
    r.z = LEAKY(v[2] + bb.z); r.w = LEAKY(v[3] + bb.w);
    *(float4*)&out[n*256 + o] = r;
  }
}

// ---------------------------------------------------------------------------
// Fused fit layers 2-4 + mean-subtract via last-block finalize.
// grid 64 (one block per atom), 512 thr. ONE device fence per block — the
// R3-measured pattern (~8 us total). 512 fences (R4) cost ~60 us: per-block
// device-fence tax dominates, never scale this pattern past ~64 blocks.
// ---------------------------------------------------------------------------
__global__ __launch_bounds__(512) void fit234_kernel(
    const float* __restrict__ h1f,
    const float* __restrict__ Wl2, const float* __restrict__ bl2,
    const float* __restrict__ Wl3, const float* __restrict__ bl3,
    const float* __restrict__ Wl4, const float* __restrict__ bl4,
    float* __restrict__ pre_g, unsigned int* __restrict__ cnt,
    float* __restrict__ out)
{
  __shared__ float h[256];
  __shared__ floatx4 red[512];
  __shared__ float h3s[128];
  __shared__ float pre_s[192];
  __shared__ int amlast;
  const int n = blockIdx.x, tid = threadIdx.x;

  if (tid < 256) h[tid] = h1f[n * 256 + tid];
  __syncthreads();

  // ---- layer 2: 256 -> 256 ----
  {
    const int o4 = tid & 63, s = tid >> 6;       // 8 slices x 32 i
    const float* Wp = Wl2 + (size_t)n * 65536 + 4 * o4;
    floatx4 acc = {0, 0, 0, 0};
    #pragma unroll 8
    for (int k = 0; k < 32; ++k) {
      const int i = s * 32 + k;
      acc += h[i] * *(const floatx4*)(Wp + (size_t)i * 256);
    }
    red[tid] = acc;
  }
  __syncthreads();
  if (tid < 64) {
    floatx4 a = red[tid];
    #pragma unroll
    for (int s = 1; s < 8; ++s) a += red[tid + s * 64];
    const float4 bb = *(const float4*)&bl2[n * 256 + 4 * tid];
    h[4*tid+0] = LEAKY(a[0] + bb.x);
    h[4*tid+1] = LEAKY(a[1] + bb.y);
    h[4*tid+2] = LEAKY(a[2] + bb.z);
    h[4*tid+3] = LEAKY(a[3] + bb.w);
  }
  __syncthreads();

  // ---- layer 3: 256 -> 128 ----
  {
    const int o4 = tid & 31, s = tid >> 5;       // 16 slices x 16 i
    const float* Wp = Wl3 + (size_t)n * 32768 + 4 * o4;
    floatx4 acc = {0, 0, 0, 0};
    #pragma unroll 8
    for (int k = 0; k < 16; ++k) {
      const int i = s * 16 + k;
      acc += h[i] * *(const floatx4*)(Wp + (size_t)i * 128);
    }
    red[tid] = acc;
  }
  __syncthreads();
  if (tid < 32) {
    floatx4 a = red[tid];
    #pragma unroll
    for (int s = 1; s < 16; ++s) a += red[tid + s * 32];
    const float4 bb = *(const float4*)&bl3[n * 128 + 4 * tid];
    h3s[4*tid+0] = LEAKY(a[0] + bb.x);
    h3s[4*tid+1] = LEAKY(a[1] + bb.y);
    h3s[4*tid+2] = LEAKY(a[2] + bb.z);
    h3s[4*tid+3] = LEAKY(a[3] + bb.w);
  }
  __syncthreads();

  // ---- layer 4: 128 -> 3 ----
  if (tid < 128) {
    const float hv = h3s[tid];
    floatx4 v;
    v[0] = hv * Wl4[(size_t)n * 384 + tid * 3 + 0];
    v[1] = hv * Wl4[(size_t)n * 384 + tid * 3 + 1];
    v[2] = hv * Wl4[(size_t)n * 384 + tid * 3 + 2];
    v[3] = 0.f;
    red[tid] = v;
  }
  __syncthreads();
  #pragma unroll
  for (int off = 64; off >= 1; off >>= 1) {
    if (tid < off) red[tid] += red[tid + off];
    __syncthreads();
  }
  if (tid < 3) {
    const float pre = red[0][tid] + bl4[n * 3 + tid];
    __hip_atomic_store(&pre_g[n * 3 + tid], pre, __ATOMIC_RELAXED,
                       __HIP_MEMORY_SCOPE_AGENT);
  }
  __threadfence();
  if (tid == 0) {
    const unsigned old = __hip_atomic_fetch_add(cnt, 1u, __ATOMIC_ACQ_REL,
                                                __HIP_MEMORY_SCOPE_AGENT);
    amlast = (old == 63u);
  }
  __syncthreads();
  if (amlast) {
    if (tid < 192)
      pre_s[tid] = __hip_atomic_load(&pre_g[tid], __ATOMIC_RELAXED,
                                     __HIP_MEMORY_SCOPE_AGENT);
    __syncthreads();
    if (tid < 3) {
      float s = 0.f;
      for (int nn = 0; nn < 64; ++nn) s += pre_s[nn * 3 + tid];
      h3s[tid] = s * (1.0f / 64.0f);   // reuse as mean store
    }
    __syncthreads();
    if (tid < 192) out[tid] = pre_s[tid] - h3s[tid % 3];
  }
}

// ---------------------------------------------------------------------------
extern "C" void kernel_launch(void* const* d_in, const int* in_sizes, int n_in,
                              void* d_out, int out_size, void* d_ws, size_t ws_size,
                              hipStream_t stream) {
  const float* x       = (const float*)d_in[0];
  const float* lattice = (const float*)d_in[1];
  const float* We1 = (const float*)d_in[2];
  const float* be1 = (const float*)d_in[3];
  const float* We2 = (const float*)d_in[4];
  const float* be2 = (const float*)d_in[5];
  const float* We3 = (const float*)d_in[6];
  const float* be3 = (const float*)d_in[7];
  const float* Wl1 = (const float*)d_in[8];
  const float* bl1 = (const float*)d_in[9];
  const float* Wl2 = (const float*)d_in[10];
  const float* bl2 = (const float*)d_in[11];
  const float* Wl3 = (const float*)d_in[12];
  const float* bl3 = (const float*)d_in[13];
  const float* Wl4 = (const float*)d_in[14];
  const float* bl4 = (const float*)d_in[15];
  const int*   types = (const int*)d_in[16];

  float* wsf = (float*)d_ws;
  float*        dsc   = wsf;                      // 24576
  float*        h1f   = wsf + 24576;              // 16384
  float*        pre_g = wsf + 40960;              // 192
  unsigned int* cnt   = (unsigned int*)(wsf + 41152);
  short*        g_WT  = (short*)(wsf + 41156);    // 33792 shorts

  prep_kernel<<<32, 256, 0, stream>>>(We1, be1, We2, We3, g_WT, dsc, cnt);
  embed_kernel<<<dim3(64, 2, 6), 256, 0, stream>>>(
      x, lattice, g_WT, be2, be3, types, dsc);
  fit1_kernel<<<dim3(64, 8), 256, 0, stream>>>(dsc, Wl1, bl1, h1f);
  fit234_kernel<<<64, 512, 0, stream>>>(h1f, Wl2, bl2, Wl3, bl3, Wl4, bl4,
                                        pre_g, cnt, (float*)d_out);
}

// Round 6
// 140.325 us; speedup vs baseline: 1.2855x; 1.0212x over previous
//
#include <hip/hip_runtime.h>

#define LEAKY(t) ((t) > 0.0f ? (t) : 0.01f*(t))

typedef __attribute__((ext_vector_type(8))) short short8;
typedef __attribute__((ext_vector_type(4))) float floatx4;

// fp32 -> bf16 (round to nearest even), bits in a short
static __device__ __forceinline__ short f2bf(float f) {
  unsigned u = __float_as_uint(f);
  u += 0x7FFFu + ((u >> 16) & 1u);
  return (short)(u >> 16);
}

// ---------------------------------------------------------------------------
// Workspace (float index):
//   d    @ 0      64*384 = 24576  descriptor (zeroed by prep, atomicAdd)
//   h1f  @ 24576  64*256
//   h2f  @ 40960  64*256
//   h3f  @ 57344  64*128
//   g_WT @ 65536  33792 shorts    MFMA B-fragment tables (lane-indexed)
// No device fences anywhere: cross-kernel visibility via stream ordering.
// (R4 lesson: per-block __threadfence costs ~0.1 us serialized — never scale
//  last-block-finalize patterns; R6 removes them entirely.)
// ---------------------------------------------------------------------------

// ---------------------------------------------------------------------------
// Prep: build MFMA B-fragment tables, zero d.
// B-frag layout for 16x16x32: lane=(col=o_local, quad), element j -> k=quad*8+j.
// Layer-1 trick: k<3 -> We1[k][o], k==3 -> be1[o] (A supplies 1.0 at k=3).
// ---------------------------------------------------------------------------
__global__ __launch_bounds__(256) void prep_kernel(
    const float* __restrict__ We1, const float* __restrict__ be1,
    const float* __restrict__ We2, const float* __restrict__ We3,
    short* __restrict__ g_WT, float* __restrict__ d)
{
  const int gt = blockIdx.x * 256 + threadIdx.x;
  const int GS = gridDim.x * 256;
  for (int i = gt; i < 6144; i += GS) {
    const float4 z = {0.f, 0.f, 0.f, 0.f};
    ((float4*)d)[i] = z;
  }
  for (int it = gt; it < 4224; it += GS) {
    short8 v;
    if (it < 384) {
      const int p = it >> 7, r = it & 127, ot = (r >> 6) & 1, ln = r & 63;
      const int col = ln & 15, quad = ln >> 4, o = ot * 16 + col;
      #pragma unroll
      for (int j = 0; j < 8; ++j) {
        const int k = quad * 8 + j;
        float f = 0.0f;
        if (k < 3) f = We1[p * 96 + k * 32 + o];
        else if (k == 3) f = be1[p * 32 + o];
        v[j] = f2bf(f);
      }
    } else if (it < 1152) {
      const int t = it - 384;
      const int p = t >> 8, r = t & 255, ot = r >> 6, ln = r & 63;
      const int col = ln & 15, quad = ln >> 4, o = ot * 16 + col;
      #pragma unroll
      for (int j = 0; j < 8; ++j) {
        const int k = quad * 8 + j;
        v[j] = f2bf(We2[p * 2048 + k * 64 + o]);
      }
    } else {
      const int t = it - 1152;
      const int p = t >> 10, r = t & 1023, ot = r >> 7, rr = r & 127;
      const int ks = rr >> 6, ln = rr & 63;
      const int col = ln & 15, quad = ln >> 4, o = ot * 16 + col;
      #pragma unroll
      for (int j = 0; j < 8; ++j) {
        const int k = ks * 32 + quad * 8 + j;
        v[j] = f2bf(We3[p * 8192 + k * 128 + o]);
      }
    }
    *(short8*)(g_WT + it * 8) = v;
  }
}

// ---------------------------------------------------------------------------
// Embedding + descriptor, all-MFMA, weights in registers (no LDS staging).
// grid (64 n, 2 par, 6 chunk), 256 thr; chunk = 144 pairs = 9 m-tiles.
// LDS only holds activations: 36.9 KB -> 4 blocks/CU.
// keep = (dist<=25) && (m!=n); pair-type p depends only on (n%2, j%2).
// Descriptor atomicAdd'ed into global d[n][o*3+c] (zeroed by prep).
// ---------------------------------------------------------------------------
__global__ __launch_bounds__(256, 4) void embed_kernel(
    const float* __restrict__ x, const float* __restrict__ lattice,
    const short* __restrict__ g_WT,
    const float* __restrict__ be2, const float* __restrict__ be3,
    const int* __restrict__ types, float* __restrict__ d)
{
  __shared__ __align__(16) float rel4[144 * 4];   // {rel0,rel1,rel2,1.0}
  __shared__ __align__(16) float rk4[144 * 4];    // rel*keep
  __shared__ __align__(16) short h1s[144 * 40];   // bf16, stride 40
  __shared__ __align__(16) short h2s[144 * 72];   // bf16, stride 72

  const int n = blockIdx.x, par = blockIdx.y, chunk = blockIdx.z;
  const int tid = threadIdx.x;
  const int lane = tid & 63, w = tid >> 6;
  const int col = lane & 15, quad = lane >> 4;

  const int tn = types[n];
  const int tj = types[par];
  const int lo = tn < tj ? tn : tj;
  const int hi = tn < tj ? tj : tn;
  const int p  = lo * 2 - (lo * (lo - 1)) / 2 + (hi - lo);

  // ---- B-fragments straight from global into registers (L2-hot) ----
  const short8* WT8 = (const short8*)g_WT;
  const short8 w1b0 = WT8[(p * 2 + 0) * 64 + lane];
  const short8 w1b1 = WT8[(p * 2 + 1) * 64 + lane];
  short8 w2b[4];
  #pragma unroll
  for (int ot = 0; ot < 4; ++ot) w2b[ot] = WT8[384 + (p * 4 + ot) * 64 + lane];
  short8 w3b[2][2];
  #pragma unroll
  for (int nt = 0; nt < 2; ++nt)
    #pragma unroll
    for (int ks = 0; ks < 2; ++ks)
      w3b[nt][ks] = WT8[1152 + ((p * 8 + 2 * w + nt) * 2 + ks) * 64 + lane];
  float bias2[4];
  #pragma unroll
  for (int ot = 0; ot < 4; ++ot) bias2[ot] = be2[p * 64 + ot * 16 + col];
  float bias3[2];
  #pragma unroll
  for (int nt = 0; nt < 2; ++nt) bias3[nt] = be3[p * 128 + w * 32 + nt * 16 + col];

  // ---- rel / keep, one thread per pair ----
  if (tid < 144) {
    const int q  = chunk * 144 + tid;
    const int c  = q >> 5;
    const int jj = q & 31;
    const int j  = 2 * jj + par;
    const float f0 = (float)(c / 9);
    const float f1 = (float)((c / 3) % 3);
    const float f2c = (float)(c % 3);
    const float rel0 = x[j*3+0] - x[n*3+0] + f0*lattice[0] + f1*lattice[3] + f2c*lattice[6];
    const float rel1 = x[j*3+1] - x[n*3+1] + f0*lattice[1] + f1*lattice[4] + f2c*lattice[7];
    const float rel2 = x[j*3+2] - x[n*3+2] + f0*lattice[2] + f1*lattice[5] + f2c*lattice[8];
    const float dist2 = rel0*rel0 + rel1*rel1 + rel2*rel2;
    const int m = c * 64 + j;
    const bool keep = (dist2 <= 625.0f) && (m != n);
    const float kf = keep ? 1.0f : 0.0f;
    rel4[tid*4+0] = rel0; rel4[tid*4+1] = rel1;
    rel4[tid*4+2] = rel2; rel4[tid*4+3] = 1.0f;
    rk4[tid*4+0] = rel0*kf; rk4[tid*4+1] = rel1*kf;
    rk4[tid*4+2] = rel2*kf; rk4[tid*4+3] = 0.0f;
  }
  __syncthreads();

  // ---- layer 1 (3->32) via MFMA, m-tiles split across waves ----
  for (int mt = w; mt < 9; mt += 4) {
    const float4 r4 = *(const float4*)&rel4[(mt*16 + col) * 4];
    short8 a = {0, 0, 0, 0, 0, 0, 0, 0};
    if (quad == 0) {
      a[0] = f2bf(r4.x); a[1] = f2bf(r4.y); a[2] = f2bf(r4.z);
      a[3] = (short)0x3F80;   // 1.0 -> picks up bias row k=3
    }
    const floatx4 z = {0.f, 0.f, 0.f, 0.f};
    const floatx4 c0 = __builtin_amdgcn_mfma_f32_16x16x32_bf16(a, w1b0, z, 0, 0, 0);
    const floatx4 c1 = __builtin_amdgcn_mfma_f32_16x16x32_bf16(a, w1b1, z, 0, 0, 0);
    #pragma unroll
    for (int r = 0; r < 4; ++r) {
      const int pair = mt*16 + quad*4 + r;
      h1s[pair*40 +      col] = f2bf(LEAKY(c0[r]));
      h1s[pair*40 + 16 + col] = f2bf(LEAKY(c1[r]));
    }
  }
  __syncthreads();

  // ---- layer 2 (32->64) via MFMA, m-tiles split across waves ----
  for (int mt = w; mt < 9; mt += 4) {
    const short8 a = *(const short8*)&h1s[(mt*16 + col) * 40 + quad*8];
    #pragma unroll
    for (int ot = 0; ot < 4; ++ot) {
      floatx4 acc = {bias2[ot], bias2[ot], bias2[ot], bias2[ot]};
      acc = __builtin_amdgcn_mfma_f32_16x16x32_bf16(a, w2b[ot], acc, 0, 0, 0);
      #pragma unroll
      for (int r = 0; r < 4; ++r) {
        const int pair = mt*16 + quad*4 + r;
        h2s[pair*72 + ot*16 + col] = f2bf(LEAKY(acc[r]));
      }
    }
  }
  __syncthreads();

  // ---- layer 3 (64->128) MFMA, wave w owns o-tiles {2w,2w+1}; fused desc ----
  float vacc[2][3] = {{0,0,0},{0,0,0}};
  for (int mt = 0; mt < 9; ++mt) {
    const short8 a0 = *(const short8*)&h2s[(mt*16 + col) * 72 +      quad*8];
    const short8 a1 = *(const short8*)&h2s[(mt*16 + col) * 72 + 32 + quad*8];
    float4 rks[4];
    #pragma unroll
    for (int r = 0; r < 4; ++r)
      rks[r] = *(const float4*)&rk4[(mt*16 + quad*4 + r) * 4];
    #pragma unroll
    for (int nt = 0; nt < 2; ++nt) {
      floatx4 acc = {bias3[nt], bias3[nt], bias3[nt], bias3[nt]};
      acc = __builtin_amdgcn_mfma_f32_16x16x32_bf16(a0, w3b[nt][0], acc, 0, 0, 0);
      acc = __builtin_amdgcn_mfma_f32_16x16x32_bf16(a1, w3b[nt][1], acc, 0, 0, 0);
      #pragma unroll
      for (int r = 0; r < 4; ++r) {
        const float h3 = LEAKY(acc[r]);
        vacc[nt][0] += h3 * rks[r].x;
        vacc[nt][1] += h3 * rks[r].y;
        vacc[nt][2] += h3 * rks[r].z;
      }
    }
  }
  #pragma unroll
  for (int nt = 0; nt < 2; ++nt)
    #pragma unroll
    for (int c = 0; c < 3; ++c) {
      float v = vacc[nt][c];
      v += __shfl_xor(v, 16, 64);
      v += __shfl_xor(v, 32, 64);
      vacc[nt][c] = v;
    }
  if (lane < 32) {
    const int nts = lane >> 4, colw = lane & 15;
    const int o = w*32 + nts*16 + colw;
    #pragma unroll
    for (int c = 0; c < 3; ++c)
      atomicAdd(&d[n*384 + o*3 + c], nts ? vacc[1][c] : vacc[0][c]);
  }
}

// ---------------------------------------------------------------------------
// Fit layer 1: d(384) -> 256. grid (64, 8 slices of 32 o), 256 thr.
// ---------------------------------------------------------------------------
__global__ __launch_bounds__(256) void fit1_kernel(
    const float* __restrict__ d, const float* __restrict__ W,
    const float* __restrict__ b, float* __restrict__ out)
{
  __shared__ float din[384];
  __shared__ floatx4 red[256];
  const int n = blockIdx.x, os = blockIdx.y * 32, tid = threadIdx.x;
  for (int i = tid; i < 384; i += 256) din[i] = d[n*384 + i];
  __syncthreads();
  const int g = tid & 7, s = tid >> 3;          // 8 o4-groups x 32 i-slices(12)
  const float* Wp = W + (size_t)n * 98304 + os + 4 * g;
  floatx4 acc = {0, 0, 0, 0};
  #pragma unroll
  for (int k = 0; k < 12; ++k) {
    const int i = s * 12 + k;
    acc += din[i] * *(const floatx4*)(Wp + (size_t)i * 256);
  }
  red[tid] = acc;
  __syncthreads();
  #pragma unroll
  for (int off = 128; off >= 8; off >>= 1) {
    if (tid < off) red[tid] += red[tid + off];
    __syncthreads();
  }
  if (tid < 8) {
    const floatx4 v = red[tid];
    const int o = os + 4 * tid;
    const float4 bb = *(const float4*)&b[n*256 + o];
    float4 r;
    r.x = LEAKY(v[0] + bb.x); r.y = LEAKY(v[1] + bb.y);
    r.z = LEAKY(v[2] + bb.z); r.w = LEAKY(v[3] + bb.w);
    *(float4*)&out[n*256 + o] = r;
  }
}

// ---------------------------------------------------------------------------
// Fit layer 2: 256 -> 256. grid (64, 8 slices of 32 o), 256 thr. No fences.
// ---------------------------------------------------------------------------
__global__ __launch_bounds__(256) void fit2_kernel(
    const float* __restrict__ in, const float* __restrict__ W,
    const float* __restrict__ b, float* __restrict__ out)
{
  __shared__ float din[256];
  __shared__ floatx4 red[256];
  const int n = blockIdx.x, os = blockIdx.y * 32, tid = threadIdx.x;
  din[tid] = in[n*256 + tid];
  __syncthreads();
  const int g = tid & 7, s = tid >> 3;          // 8 o4-groups x 32 i-slices(8)
  const float* Wp = W + (size_t)n * 65536 + os + 4 * g;
  floatx4 acc = {0, 0, 0, 0};
  #pragma unroll
  for (int k = 0; k < 8; ++k) {
    const int i = s * 8 + k;
    acc += din[i] * *(const floatx4*)(Wp + (size_t)i * 256);
  }
  red[tid] = acc;
  __syncthreads();
  #pragma unroll
  for (int off = 128; off >= 8; off >>= 1) {
    if (tid < off) red[tid] += red[tid + off];
    __syncthreads();
  }
  if (tid < 8) {
    const floatx4 v = red[tid];
    const int o = os + 4 * tid;
    const float4 bb = *(const float4*)&b[n*256 + o];
    float4 r;
    r.x = LEAKY(v[0] + bb.x); r.y = LEAKY(v[1] + bb.y);
    r.z = LEAKY(v[2] + bb.z); r.w = LEAKY(v[3] + bb.w);
    *(float4*)&out[n*256 + o] = r;
  }
}

// ---------------------------------------------------------------------------
// Fit layer 3: 256 -> 128. grid (64, 8 slices of 16 o), 256 thr. Plain stores.
// ---------------------------------------------------------------------------
__global__ __launch_bounds__(256) void fit3_kernel(
    const float* __restrict__ in, const float* __restrict__ W,
    const float* __restrict__ b, float* __restrict__ out)
{
  __shared__ float din[256];
  __shared__ floatx4 red[256];
  const int n = blockIdx.x, os = blockIdx.y * 16, tid = threadIdx.x;
  din[tid] = in[n*256 + tid];
  __syncthreads();
  const int g = tid & 3, s = tid >> 2;          // 4 o4-groups x 64 i-slices(4)
  const float* Wp = W + (size_t)n * 32768 + os + 4 * g;
  floatx4 acc = {0, 0, 0, 0};
  #pragma unroll
  for (int k = 0; k < 4; ++k) {
    const int i = s * 4 + k;
    acc += din[i] * *(const floatx4*)(Wp + (size_t)i * 128);
  }
  red[tid] = acc;
  __syncthreads();
  #pragma unroll
  for (int off = 128; off >= 4; off >>= 1) {
    if (tid < off) red[tid] += red[tid + off];
    __syncthreads();
  }
  if (tid < 4) {
    const floatx4 v = red[tid];
    const int o = os + 4 * tid;
    const float4 bb = *(const float4*)&b[n*128 + o];
    float4 r;
    r.x = LEAKY(v[0] + bb.x); r.y = LEAKY(v[1] + bb.y);
    r.z = LEAKY(v[2] + bb.z); r.w = LEAKY(v[3] + bb.w);
    *(float4*)&out[n*128 + o] = r;
  }
}

// ---------------------------------------------------------------------------
// Fit layer 4 (128 -> 3, no activation) + mean-subtract. 1 block, 256 thr.
// ---------------------------------------------------------------------------
__global__ __launch_bounds__(256) void fit4_kernel(
    const float* __restrict__ h3, const float* __restrict__ W,
    const float* __restrict__ b, float* __restrict__ out)
{
  __shared__ float part[256 * 3];
  __shared__ float pre[192];
  __shared__ float meanv[3];
  const int tid = threadIdx.x;
  const int n = tid >> 2, q = tid & 3;
  const float* Wn = W + (size_t)n * 384;
  const float* h  = h3 + n * 128;
  float a0 = 0.f, a1 = 0.f, a2 = 0.f;
  for (int k = 0; k < 32; ++k) {
    const int i = q * 32 + k;
    const float hv = h[i];
    a0 += hv * Wn[i*3 + 0];
    a1 += hv * Wn[i*3 + 1];
    a2 += hv * Wn[i*3 + 2];
  }
  part[tid*3+0] = a0; part[tid*3+1] = a1; part[tid*3+2] = a2;
  __syncthreads();
  if (tid < 192) {
    const int nn = tid / 3, o = tid % 3;
    float t = part[(nn*4+0)*3+o] + part[(nn*4+1)*3+o]
            + part[(nn*4+2)*3+o] + part[(nn*4+3)*3+o] + b[tid];
    pre[tid] = t;
  }
  __syncthreads();
  if (tid < 3) {
    float s = 0.f;
    for (int nn = 0; nn < 64; ++nn) s += pre[nn*3 + tid];
    meanv[tid] = s * (1.0f / 64.0f);
  }
  __syncthreads();
  if (tid < 192) out[tid] = pre[tid] - meanv[tid % 3];
}

// ---------------------------------------------------------------------------
extern "C" void kernel_launch(void* const* d_in, const int* in_sizes, int n_in,
                              void* d_out, int out_size, void* d_ws, size_t ws_size,
                              hipStream_t stream) {
  const float* x       = (const float*)d_in[0];
  const float* lattice = (const float*)d_in[1];
  const float* We1 = (const float*)d_in[2];
  const float* be1 = (const float*)d_in[3];
  const float* We2 = (const float*)d_in[4];
  const float* be2 = (const float*)d_in[5];
  const float* We3 = (const float*)d_in[6];
  const float* be3 = (const float*)d_in[7];
  const float* Wl1 = (const float*)d_in[8];
  const float* bl1 = (const float*)d_in[9];
  const float* Wl2 = (const float*)d_in[10];
  const float* bl2 = (const float*)d_in[11];
  const float* Wl3 = (const float*)d_in[12];
  const float* bl3 = (const float*)d_in[13];
  const float* Wl4 = (const float*)d_in[14];
  const float* bl4 = (const float*)d_in[15];
  const int*   types = (const int*)d_in[16];

  float* wsf = (float*)d_ws;
  float* dsc  = wsf;                      // 24576
  float* h1f  = wsf + 24576;              // 16384
  float* h2f  = wsf + 40960;              // 16384
  float* h3f  = wsf + 57344;              // 8192
  short* g_WT = (short*)(wsf + 65536);    // 33792 shorts

  prep_kernel<<<32, 256, 0, stream>>>(We1, be1, We2, We3, g_WT, dsc);
  embed_kernel<<<dim3(64, 2, 6), 256, 0, stream>>>(
      x, lattice, g_WT, be2, be3, types, dsc);
  fit1_kernel<<<dim3(64, 8), 256, 0, stream>>>(dsc, Wl1, bl1, h1f);
  fit2_kernel<<<dim3(64, 8), 256, 0, stream>>>(h1f, Wl2, bl2, h2f);
  fit3_kernel<<<dim3(64, 8), 256, 0, stream>>>(h2f, Wl3, bl3, h3f);
  fit4_kernel<<<1, 256, 0, stream>>>(h3f, Wl4, bl4, (float*)d_out);
}